// Round 7
// baseline (139.093 us; speedup 1.0000x reference)
//
#include <hip/hip_runtime.h>

static constexpr int IMG = 512;
static constexpr int TX  = 64;            // tile width  (output)
static constexpr int TY  = 16;            // tile height (output)
static constexpr int LST = 76;            // LDS row stride floats; 76/4=19 (odd #f4) de-phases b128 banks
static constexpr int SROWS  = TY + 6;     // 22 staged rows (r <-> y = ty0-3+r)
static constexpr int NSTAGE = SROWS * 19; // 418 float4 staging items (last group = dead pad)

// One diffusion step, single-wave block, 4 px/thread, prefetch-pipelined,
// phase-split math for wide trans-pipe ILP.
// Column maps: A(X0): x = tx0-4+c ; B(X1): x = tx0-2+c ; A(X2): x = tx0-1+c.
template<int WOFF, int NR, int RLO, int NG, bool TO_GLOBAL>
__device__ __forceinline__ void diffuse_step(
    const float* __restrict__ prev, float* __restrict__ cur,
    const float* __restrict__ Wt, const float* __restrict__ bt,
    int xoff, int ty0, int tx0, int tid, float* __restrict__ gout)
{
    constexpr int LOADW  = WOFF ? 8 : 6;
    constexpr int NITEMS = NR * NG;

    float L0[LOADW], L1[LOADW], L2[LOADW];
    {   // initial load (clamped)
        const int idx0 = (tid < NITEMS) ? tid : 0;
        const int rr = idx0 / NG, j = idx0 - rr * NG;
        const float* base = prev + (RLO + rr - 1) * LST + 4 * j;
        *(float4*)&L0[0] = *(const float4*)(base);
        *(float4*)&L1[0] = *(const float4*)(base + LST);
        *(float4*)&L2[0] = *(const float4*)(base + 2 * LST);
        if (WOFF) {
            *(float4*)&L0[4] = *(const float4*)(base + 4);
            *(float4*)&L1[4] = *(const float4*)(base + LST + 4);
            *(float4*)&L2[4] = *(const float4*)(base + 2 * LST + 4);
        } else {
            *(float2*)&L0[4] = *(const float2*)(base + 4);
            *(float2*)&L1[4] = *(const float2*)(base + LST + 4);
            *(float2*)&L2[4] = *(const float2*)(base + 2 * LST + 4);
        }
    }

    for (int idx = tid; idx < NITEMS; idx += 64) {
        // ---- prefetch next item's window ----
        float P0[LOADW], P1[LOADW], P2[LOADW];
        {
            const int nidx = (idx + 64 < NITEMS) ? (idx + 64) : idx;
            const int rr = nidx / NG, j = nidx - rr * NG;
            const float* base = prev + (RLO + rr - 1) * LST + 4 * j;
            *(float4*)&P0[0] = *(const float4*)(base);
            *(float4*)&P1[0] = *(const float4*)(base + LST);
            *(float4*)&P2[0] = *(const float4*)(base + 2 * LST);
            if (WOFF) {
                *(float4*)&P0[4] = *(const float4*)(base + 4);
                *(float4*)&P1[4] = *(const float4*)(base + LST + 4);
                *(float4*)&P2[4] = *(const float4*)(base + 2 * LST + 4);
            } else {
                *(float2*)&P0[4] = *(const float2*)(base + 4);
                *(float2*)&P1[4] = *(const float2*)(base + LST + 4);
                *(float2*)&P2[4] = *(const float2*)(base + 2 * LST + 4);
            }
        }

        const int rr = idx / NG, j = idx - rr * NG;
        const int r  = RLO + rr, c0 = 4 * j;

        // ---- phase 1: all 32 conv results ----
        float d[32];
#pragma unroll
        for (int k = 0; k < 8; ++k) {
            const float w0 = Wt[9*k+0], w1 = Wt[9*k+1], w2 = Wt[9*k+2];
            const float w3 = Wt[9*k+3], w4 = Wt[9*k+4], w5 = Wt[9*k+5];
            const float w6 = Wt[9*k+6], w7 = Wt[9*k+7], w8 = Wt[9*k+8];
            const float bk = bt[k];
#pragma unroll
            for (int i = 0; i < 4; ++i) {
                float dd = bk;
                dd = fmaf(w0, L0[WOFF+i],   dd);
                dd = fmaf(w1, L0[WOFF+i+1], dd);
                dd = fmaf(w2, L0[WOFF+i+2], dd);
                dd = fmaf(w3, L1[WOFF+i],   dd);
                dd = fmaf(w4, L1[WOFF+i+1], dd);
                dd = fmaf(w5, L1[WOFF+i+2], dd);
                dd = fmaf(w6, L2[WOFF+i],   dd);
                dd = fmaf(w7, L2[WOFF+i+1], dd);
                dd = fmaf(w8, L2[WOFF+i+2], dd);
                d[k*4+i] = dd;
            }
        }

        // ---- phase 2: 32 independent rcp (fills trans pipe, latency overlapped) ----
        float e[32];
#pragma unroll
        for (int q = 0; q < 32; ++q)
            e[q] = __builtin_amdgcn_rcpf(fmaf(d[q], d[q], 1.0f));
        // ---- phase 3: 32 independent exp2 ----
#pragma unroll
        for (int q = 0; q < 32; ++q)
            e[q] = __builtin_amdgcn_exp2f(
                       -1.442695040888963f * __builtin_fabsf(d[q]) * e[q]);
        // ---- phase 4: accumulate ----
        float acc[4] = {0.f, 0.f, 0.f, 0.f};
#pragma unroll
        for (int k = 0; k < 8; ++k)
#pragma unroll
            for (int i = 0; i < 4; ++i)
                acc[i] = fmaf(e[k*4+i], d[k*4+i], acc[i]);

        float4 v;
        v.x = L1[WOFF+1] - acc[0] * 0.125f;
        v.y = L1[WOFF+2] - acc[1] * 0.125f;
        v.z = L1[WOFF+3] - acc[2] * 0.125f;
        v.w = L1[WOFF+4] - acc[3] * 0.125f;

        const int gy = ty0 - 3 + r;
        if (TO_GLOBAL) {
            *(float4*)&gout[gy * IMG + tx0 + c0] = v;
        } else {
            const bool ry  = (unsigned)gy < (unsigned)IMG;
            const int  gx0 = xoff + c0;
            v.x = (ry && (unsigned)(gx0 + 0) < (unsigned)IMG) ? v.x : 0.f;
            v.y = (ry && (unsigned)(gx0 + 1) < (unsigned)IMG) ? v.y : 0.f;
            v.z = (ry && (unsigned)(gx0 + 2) < (unsigned)IMG) ? v.z : 0.f;
            v.w = (ry && (unsigned)(gx0 + 3) < (unsigned)IMG) ? v.w : 0.f;
            *(float4*)&cur[r * LST + c0] = v;
        }

#pragma unroll
        for (int q = 0; q < LOADW; ++q) { L0[q] = P0[q]; L1[q] = P1[q]; L2[q] = P2[q]; }
    }
}

__global__ __launch_bounds__(64, 4) void deep_ad_kernel(
    const float* __restrict__ x, const float* __restrict__ W,
    const float* __restrict__ b, float* __restrict__ out)
{
    __shared__ float A[SROWS * LST];   // X0, later reused for X2
    __shared__ float Bs[SROWS * LST];  // X1

    const int tid = threadIdx.x;
    const int tx0 = blockIdx.x * TX;
    const int ty0 = blockIdx.y * TY;
    const float* xin  = x   + (size_t)blockIdx.z * (IMG * IMG);
    float*       gout = out + (size_t)blockIdx.z * (IMG * IMG);

    // Stage X0 (22 rows x 19 float4 groups): batched loads, one wait, LDS writes.
    // Note A[item*4] == A[rr*LST + 4*j] since LST = 4*19.
    {
        float4 sv[7];
#pragma unroll
        for (int q = 0; q < 7; ++q) {
            const int item = tid + 64 * q;
            const int rr = item / 19, j = item - rr * 19;
            const int gy = ty0 - 3 + rr;
            const int gx = tx0 - 4 + 4 * j;
            float4 v = {0.f, 0.f, 0.f, 0.f};
            if (item < NSTAGE && (unsigned)gy < (unsigned)IMG && (unsigned)gx < (unsigned)IMG)
                v = *(const float4*)(xin + gy * IMG + gx);
            sv[q] = v;
        }
#pragma unroll
        for (int q = 0; q < 7; ++q) {
            const int item = tid + 64 * q;
            if (item < NSTAGE) *(float4*)&A[item * 4] = sv[q];
        }
    }
    __syncthreads();   // single-wave block: cheap

    // step1: rows r=1..20 (y: ty0-2..ty0+17), 17 groups (x: tx0-2..tx0+65) -> Bs
    diffuse_step<1, TY + 4, 1, 17, false>(A,  Bs, W + 0,   b + 0,  tx0 - 2, ty0, tx0, tid, nullptr);
    __syncthreads();
    // step2: rows r=2..19, 17 groups (x: tx0-1..tx0+66; overhang dead) -> A
    diffuse_step<0, TY + 2, 2, 17, false>(Bs, A,  W + 72,  b + 8,  tx0 - 1, ty0, tx0, tid, nullptr);
    __syncthreads();
    // step3: rows r=3..18 (y: ty0..ty0+15), 16 groups (x: tx0..tx0+63) -> global
    diffuse_step<0, TY,     3, 16, true >(A, nullptr, W + 144, b + 16, 0, ty0, tx0, tid, gout);
}

extern "C" void kernel_launch(void* const* d_in, const int* in_sizes, int n_in,
                              void* d_out, int out_size, void* d_ws, size_t ws_size,
                              hipStream_t stream)
{
    const float* x = (const float*)d_in[0];
    const float* W = (const float*)d_in[1];  // [3,8,1,3,3]
    const float* b = (const float*)d_in[2];  // [3,8]
    float* out = (float*)d_out;
    const int N = in_sizes[0] / (IMG * IMG); // 16
    dim3 grid(IMG / TX, IMG / TY, N);
    deep_ad_kernel<<<grid, 64, 0, stream>>>(x, W, b, out);
}

// Round 8
// 115.256 us; speedup vs baseline: 1.2068x; 1.2068x over previous
//
#include <hip/hip_runtime.h>

static constexpr int IMG = 512;

__device__ __forceinline__ float gd_acc(float d, float acc) {
    const float t    = fmaf(d, d, 1.0f);
    const float rinv = __builtin_amdgcn_rcpf(t);
    const float e    = __builtin_amdgcn_exp2f(
                           -1.442695040888963f * __builtin_fabsf(d) * rinv);
    return fmaf(e, d, acc);
}

// -------- One diffusion step, global -> global. No LDS, no barriers. --------
// Thread: 4 px along x. Loads rows y-1..y+1, cols x0-4..x0+7 (3 aligned float4
// per row); pixel i window = L[i+3..i+5]. Edge threads take predicated path.
__global__ __launch_bounds__(256) void ad_step(
    const float* __restrict__ in, float* __restrict__ outp,
    const float* __restrict__ Wt, const float* __restrict__ bt)
{
    const int tid = threadIdx.x;
    const int x0  = blockIdx.x * 64 + (tid & 15) * 4;   // 0,4,...,508
    const int y   = blockIdx.y * 16 + (tid >> 4);       // 0..511
    const float* __restrict__ src = in + (size_t)blockIdx.z * (IMG * IMG);

    float L[3][12];
    const bool xfast = (x0 >= 4) && (x0 <= 504);        // cols x0-4..x0+7 in-image
#pragma unroll
    for (int dy = 0; dy < 3; ++dy) {
        const int yy = y + dy - 1;
        const bool rowok = (unsigned)yy < (unsigned)IMG;
        if (xfast && rowok) {
            const float* p = src + yy * IMG + x0 - 4;   // 16B-aligned
            *(float4*)&L[dy][0] = *(const float4*)(p);
            *(float4*)&L[dy][4] = *(const float4*)(p + 4);
            *(float4*)&L[dy][8] = *(const float4*)(p + 8);
        } else {
#pragma unroll
            for (int j = 0; j < 12; ++j) {
                const int col = x0 - 4 + j;
                L[dy][j] = (rowok && (unsigned)col < (unsigned)IMG)
                               ? src[yy * IMG + col] : 0.f;
            }
        }
    }

    float acc[4] = {0.f, 0.f, 0.f, 0.f};
#pragma unroll
    for (int k = 0; k < 8; ++k) {
        const float w0 = Wt[9*k+0], w1 = Wt[9*k+1], w2 = Wt[9*k+2];
        const float w3 = Wt[9*k+3], w4 = Wt[9*k+4], w5 = Wt[9*k+5];
        const float w6 = Wt[9*k+6], w7 = Wt[9*k+7], w8 = Wt[9*k+8];
        const float bk = bt[k];
#pragma unroll
        for (int i = 0; i < 4; ++i) {
            float d = bk;
            d = fmaf(w0, L[0][i+3], d);
            d = fmaf(w1, L[0][i+4], d);
            d = fmaf(w2, L[0][i+5], d);
            d = fmaf(w3, L[1][i+3], d);
            d = fmaf(w4, L[1][i+4], d);
            d = fmaf(w5, L[1][i+5], d);
            d = fmaf(w6, L[2][i+3], d);
            d = fmaf(w7, L[2][i+4], d);
            d = fmaf(w8, L[2][i+5], d);
            acc[i] = gd_acc(d, acc[i]);
        }
    }

    float4 v;
    v.x = L[1][4] - acc[0] * 0.125f;
    v.y = L[1][5] - acc[1] * 0.125f;
    v.z = L[1][6] - acc[2] * 0.125f;
    v.w = L[1][7] - acc[3] * 0.125f;
    *(float4*)&outp[(size_t)blockIdx.z * (IMG * IMG) + y * IMG + x0] = v;
}

// -------- Fallback: R4 fused kernel (used only if ws_size < one image) --------
static constexpr int TXF = 64;
static constexpr int TYF = 16;
static constexpr int LST = 72;
static constexpr int SROWS  = TYF + 6;
static constexpr int NSTAGE = SROWS * 18;

template<int WOFF, int NR, int RLO, int NG, bool TO_GLOBAL>
__device__ __forceinline__ void diffuse_step(
    const float* __restrict__ prev, float* __restrict__ cur,
    const float* __restrict__ Wt, const float* __restrict__ bt,
    int xoff, int ty0, int tx0, int tid, float* __restrict__ gout)
{
    constexpr int LOADW  = WOFF ? 8 : 6;
    constexpr int NITEMS = NR * NG;

    float L0[LOADW], L1[LOADW], L2[LOADW];
    {
        const int idx0 = (tid < NITEMS) ? tid : 0;
        const int rr = idx0 / NG, j = idx0 - rr * NG;
        const float* base = prev + (RLO + rr - 1) * LST + 4 * j;
        *(float4*)&L0[0] = *(const float4*)(base);
        *(float4*)&L1[0] = *(const float4*)(base + LST);
        *(float4*)&L2[0] = *(const float4*)(base + 2 * LST);
        if (WOFF) {
            *(float4*)&L0[4] = *(const float4*)(base + 4);
            *(float4*)&L1[4] = *(const float4*)(base + LST + 4);
            *(float4*)&L2[4] = *(const float4*)(base + 2 * LST + 4);
        } else {
            *(float2*)&L0[4] = *(const float2*)(base + 4);
            *(float2*)&L1[4] = *(const float2*)(base + LST + 4);
            *(float2*)&L2[4] = *(const float2*)(base + 2 * LST + 4);
        }
    }

    for (int idx = tid; idx < NITEMS; idx += 64) {
        float P0[LOADW], P1[LOADW], P2[LOADW];
        {
            const int nidx = (idx + 64 < NITEMS) ? (idx + 64) : idx;
            const int rr = nidx / NG, j = nidx - rr * NG;
            const float* base = prev + (RLO + rr - 1) * LST + 4 * j;
            *(float4*)&P0[0] = *(const float4*)(base);
            *(float4*)&P1[0] = *(const float4*)(base + LST);
            *(float4*)&P2[0] = *(const float4*)(base + 2 * LST);
            if (WOFF) {
                *(float4*)&P0[4] = *(const float4*)(base + 4);
                *(float4*)&P1[4] = *(const float4*)(base + LST + 4);
                *(float4*)&P2[4] = *(const float4*)(base + 2 * LST + 4);
            } else {
                *(float2*)&P0[4] = *(const float2*)(base + 4);
                *(float2*)&P1[4] = *(const float2*)(base + LST + 4);
                *(float2*)&P2[4] = *(const float2*)(base + 2 * LST + 4);
            }
        }

        const int rr = idx / NG, j = idx - rr * NG;
        const int r  = RLO + rr, c0 = 4 * j;

        float acc[4] = {0.f, 0.f, 0.f, 0.f};
#pragma unroll
        for (int k = 0; k < 8; ++k) {
            const float w0 = Wt[9*k+0], w1 = Wt[9*k+1], w2 = Wt[9*k+2];
            const float w3 = Wt[9*k+3], w4 = Wt[9*k+4], w5 = Wt[9*k+5];
            const float w6 = Wt[9*k+6], w7 = Wt[9*k+7], w8 = Wt[9*k+8];
            const float bk = bt[k];
#pragma unroll
            for (int i = 0; i < 4; ++i) {
                float d = bk;
                d = fmaf(w0, L0[WOFF+i],   d);
                d = fmaf(w1, L0[WOFF+i+1], d);
                d = fmaf(w2, L0[WOFF+i+2], d);
                d = fmaf(w3, L1[WOFF+i],   d);
                d = fmaf(w4, L1[WOFF+i+1], d);
                d = fmaf(w5, L1[WOFF+i+2], d);
                d = fmaf(w6, L2[WOFF+i],   d);
                d = fmaf(w7, L2[WOFF+i+1], d);
                d = fmaf(w8, L2[WOFF+i+2], d);
                acc[i] = gd_acc(d, acc[i]);
            }
        }

        float4 v;
        v.x = L1[WOFF+1] - acc[0] * 0.125f;
        v.y = L1[WOFF+2] - acc[1] * 0.125f;
        v.z = L1[WOFF+3] - acc[2] * 0.125f;
        v.w = L1[WOFF+4] - acc[3] * 0.125f;

        const int gy = ty0 - 3 + r;
        if (TO_GLOBAL) {
            *(float4*)&gout[gy * IMG + tx0 + c0] = v;
        } else {
            const bool ry  = (unsigned)gy < (unsigned)IMG;
            const int  gx0 = xoff + c0;
            v.x = (ry && (unsigned)(gx0 + 0) < (unsigned)IMG) ? v.x : 0.f;
            v.y = (ry && (unsigned)(gx0 + 1) < (unsigned)IMG) ? v.y : 0.f;
            v.z = (ry && (unsigned)(gx0 + 2) < (unsigned)IMG) ? v.z : 0.f;
            v.w = (ry && (unsigned)(gx0 + 3) < (unsigned)IMG) ? v.w : 0.f;
            *(float4*)&cur[r * LST + c0] = v;
        }

#pragma unroll
        for (int q = 0; q < LOADW; ++q) { L0[q] = P0[q]; L1[q] = P1[q]; L2[q] = P2[q]; }
    }
}

__global__ __launch_bounds__(64) void deep_ad_fused(
    const float* __restrict__ x, const float* __restrict__ W,
    const float* __restrict__ b, float* __restrict__ out)
{
    __shared__ float A[SROWS * LST];
    __shared__ float Bs[SROWS * LST];

    const int tid = threadIdx.x;
    const int tx0 = blockIdx.x * TXF;
    const int ty0 = blockIdx.y * TYF;
    const float* xin  = x   + (size_t)blockIdx.z * (IMG * IMG);
    float*       gout = out + (size_t)blockIdx.z * (IMG * IMG);

    {
        float4 sv[7];
#pragma unroll
        for (int q = 0; q < 7; ++q) {
            const int item = tid + 64 * q;
            const int rr = item / 18, j = item - rr * 18;
            const int gy = ty0 - 3 + rr;
            const int gx = tx0 - 4 + 4 * j;
            float4 v = {0.f, 0.f, 0.f, 0.f};
            if (item < NSTAGE && (unsigned)gy < (unsigned)IMG && (unsigned)gx < (unsigned)IMG)
                v = *(const float4*)(xin + gy * IMG + gx);
            sv[q] = v;
        }
#pragma unroll
        for (int q = 0; q < 7; ++q) {
            const int item = tid + 64 * q;
            if (item < NSTAGE) *(float4*)&A[item * 4] = sv[q];
        }
    }
    __syncthreads();

    diffuse_step<1, TYF + 4, 1, 17, false>(A,  Bs, W + 0,   b + 0,  tx0 - 2, ty0, tx0, tid, nullptr);
    __syncthreads();
    diffuse_step<0, TYF + 2, 2, 17, false>(Bs, A,  W + 72,  b + 8,  tx0 - 1, ty0, tx0, tid, nullptr);
    __syncthreads();
    diffuse_step<0, TYF,     3, 16, true >(A, nullptr, W + 144, b + 16, 0, ty0, tx0, tid, gout);
}

extern "C" void kernel_launch(void* const* d_in, const int* in_sizes, int n_in,
                              void* d_out, int out_size, void* d_ws, size_t ws_size,
                              hipStream_t stream)
{
    const float* x = (const float*)d_in[0];
    const float* W = (const float*)d_in[1];  // [3,8,1,3,3]
    const float* b = (const float*)d_in[2];  // [3,8]
    float* out = (float*)d_out;
    const int N = in_sizes[0] / (IMG * IMG); // 16

    const size_t imgBytes = (size_t)N * IMG * IMG * sizeof(float);
    if (ws_size >= imgBytes) {
        float* ws = (float*)d_ws;
        dim3 g(IMG / 64, IMG / 16, N);       // (8, 32, 16)
        // x -> out -> ws -> out  (each step fully writes its dest before reads)
        ad_step<<<g, 256, 0, stream>>>(x,   out, W + 0,   b + 0);
        ad_step<<<g, 256, 0, stream>>>(out, ws,  W + 72,  b + 8);
        ad_step<<<g, 256, 0, stream>>>(ws,  out, W + 144, b + 16);
    } else {
        dim3 grid(IMG / TXF, IMG / TYF, N);
        deep_ad_fused<<<grid, 64, 0, stream>>>(x, W, b, out);
    }
}